// Round 12
// baseline (340.995 us; speedup 1.0000x reference)
//
#include <hip/hip_runtime.h>

#define D_MODEL 1024
#define T_SEQ   2048
#define BATCH   2
#define HEADS   16
#define DKH     64
#define M_ROWS  (BATCH*T_SEQ)   // 4096
#define OUT0_SZ (M_ROWS*D_MODEL)  // 4194304

typedef short bf16x8 __attribute__((ext_vector_type(8)));
typedef float f32x4  __attribute__((ext_vector_type(4)));
typedef unsigned short u16x4 __attribute__((ext_vector_type(4)));

__device__ __forceinline__ unsigned short f2bf(float f) {
    unsigned u = __builtin_bit_cast(unsigned, f);
    u = (u + 0x7fffu + ((u >> 16) & 1u)) >> 16;
    return (unsigned short)u;
}

__device__ __forceinline__ void gload_lds16(const void* g, void* l) {
    __builtin_amdgcn_global_load_lds(
        (const __attribute__((address_space(1))) void*)g,
        (__attribute__((address_space(3))) void*)l, 16, 0, 0);
}

// ---------------- fp32 -> bf16 convert ----------------
__global__ __launch_bounds__(256) void k_cvt(const float* __restrict__ in,
                                             unsigned short* __restrict__ out, int n4) {
    int i = blockIdx.x * 256 + threadIdx.x;
    if (i >= n4) return;
    float4 v = reinterpret_cast<const float4*>(in)[i];
    ushort4 o;
    o.x = f2bf(v.x); o.y = f2bf(v.y); o.z = f2bf(v.z); o.w = f2bf(v.w);
    reinterpret_cast<ushort4*>(out)[i] = o;
}

// all four weight matrices in one launch (grid.y selects)
__global__ __launch_bounds__(256) void k_cvt_w(const float* __restrict__ w0,
                                               const float* __restrict__ w1,
                                               const float* __restrict__ w2,
                                               const float* __restrict__ w3,
                                               unsigned short* __restrict__ out) {
    const float* src = (blockIdx.y == 0) ? w0 : (blockIdx.y == 1) ? w1 : (blockIdx.y == 2) ? w2 : w3;
    int i = blockIdx.x * 256 + threadIdx.x;          // 262144 float4s per matrix
    float4 v = reinterpret_cast<const float4*>(src)[i];
    ushort4 o;
    o.x = f2bf(v.x); o.y = f2bf(v.y); o.z = f2bf(v.z); o.w = f2bf(v.w);
    reinterpret_cast<ushort4*>(out + (size_t)blockIdx.y * 1048576)[i] = o;
}

// ---------------- shared 128x128 GEMM core (C = A * W^T), K = 1024 ----------------
__device__ __forceinline__ void stage_tile(const unsigned short* __restrict__ g,
                                           int r0, int k0, unsigned short* s, int tid) {
#pragma unroll
    for (int it = 0; it < 4; ++it) {
        int row   = (tid >> 3) + it * 32;
        int kb_sw = (tid & 7) << 4;
        int kb    = kb_sw ^ ((row & 7) << 4);
        const unsigned short* gp = g + (size_t)(r0 + row) * D_MODEL + k0 + (kb >> 1);
        gload_lds16(gp, s + (tid >> 6) * 512 + it * 2048);
    }
}

__device__ __forceinline__ bf16x8 ld_frag(const unsigned short* s, int row, int kbyte) {
    int off = (row << 7) + (kbyte ^ ((row & 7) << 4));
    return *reinterpret_cast<const bf16x8*>(reinterpret_cast<const char*>(s) + off);
}

__device__ __forceinline__ void gemm_core(const unsigned short* __restrict__ A,
                                          const unsigned short* __restrict__ W,
                                          unsigned short* sA, unsigned short* sB,
                                          int m0, int n0, f32x4 (&acc)[4][4], int tid) {
    int lane = tid & 63, lr = lane & 15, lg = lane >> 4;
    int wm = tid >> 7, wn = (tid >> 6) & 1;
#pragma unroll 1
    for (int k0 = 0; k0 < D_MODEL; k0 += 64) {
        stage_tile(A, m0, k0, sA, tid);
        stage_tile(W, n0, k0, sB, tid);
        __syncthreads();
#pragma unroll
        for (int kk = 0; kk < 2; ++kk) {
            bf16x8 a[4], b[4];
#pragma unroll
            for (int f = 0; f < 4; ++f) {
                a[f] = ld_frag(sA, wm * 64 + f * 16 + lr, kk * 64 + lg * 16);
                b[f] = ld_frag(sB, wn * 64 + f * 16 + lr, kk * 64 + lg * 16);
            }
#pragma unroll
            for (int i = 0; i < 4; ++i)
#pragma unroll
                for (int j = 0; j < 4; ++j)
                    acc[i][j] = __builtin_amdgcn_mfma_f32_16x16x32_bf16(a[i], b[j], acc[i][j], 0, 0, 0);
        }
        __syncthreads();
    }
}

// ---------------- QKV projection ----------------
__global__ __launch_bounds__(256) void k_gemm_qkv(const unsigned short* __restrict__ Xb,
                                                  const unsigned short* __restrict__ Wb,
                                                  const float* __restrict__ bq,
                                                  const float* __restrict__ bk,
                                                  const float* __restrict__ bv,
                                                  unsigned short* __restrict__ Qb,
                                                  unsigned short* __restrict__ Kb,
                                                  unsigned short* __restrict__ Vt) {
    __shared__ unsigned short sA[128 * 64];
    __shared__ unsigned short sB[128 * 64];
    int tid = threadIdx.x;
    int m0 = blockIdx.x * 128, n0 = blockIdx.y * 128, z = blockIdx.z;
    const unsigned short* W = Wb + (size_t)z * (D_MODEL * D_MODEL);
    const float* bias = (z == 0) ? bq : (z == 1) ? bk : bv;
    f32x4 acc[4][4];
#pragma unroll
    for (int i = 0; i < 4; ++i)
#pragma unroll
        for (int j = 0; j < 4; ++j) acc[i][j] = (f32x4){0.f, 0.f, 0.f, 0.f};

    gemm_core(Xb, W, sA, sB, m0, n0, acc, tid);

    int lane = tid & 63, lr = lane & 15, lg = lane >> 4;
    int wm = tid >> 7, wn = (tid >> 6) & 1;
    float scl = (z == 0) ? 0.125f : 1.0f;   // fold 1/sqrt(64) into Q
#pragma unroll
    for (int i = 0; i < 4; ++i) {
#pragma unroll
        for (int j = 0; j < 4; ++j) {
            int col = n0 + wn * 64 + j * 16 + lr;       // n = h*64 + d
            float bb = bias[col];
            int h = col >> 6, d = col & 63;
#pragma unroll
            for (int q = 0; q < 4; ++q) {
                int row = m0 + wm * 64 + i * 16 + lg * 4 + q;  // b*T + t
                int b = row >> 11, tt = row & 2047;
                float v = (acc[i][j][q] + bb) * scl;
                unsigned short h16 = f2bf(v);
                size_t bh = (size_t)b * HEADS + h;
                if (z == 2)      Vt[(bh * DKH + d) * T_SEQ + tt] = h16;          // V transposed [bh][d][t]
                else if (z == 0) Qb[(bh * T_SEQ + tt) * DKH + d] = h16;
                else             Kb[(bh * T_SEQ + tt) * DKH + d] = h16;
            }
        }
    }
}

// ---------------- output projection ----------------
__global__ __launch_bounds__(256) void k_gemm_o(const unsigned short* __restrict__ Ctx,
                                                const unsigned short* __restrict__ Wo,
                                                const float* __restrict__ bo,
                                                float* __restrict__ out) {
    __shared__ unsigned short sA[128 * 64];
    __shared__ unsigned short sB[128 * 64];
    int tid = threadIdx.x;
    int m0 = blockIdx.x * 128, n0 = blockIdx.y * 128;
    f32x4 acc[4][4];
#pragma unroll
    for (int i = 0; i < 4; ++i)
#pragma unroll
        for (int j = 0; j < 4; ++j) acc[i][j] = (f32x4){0.f, 0.f, 0.f, 0.f};

    gemm_core(Ctx, Wo, sA, sB, m0, n0, acc, tid);

    int lane = tid & 63, lr = lane & 15, lg = lane >> 4;
    int wm = tid >> 7, wn = (tid >> 6) & 1;
#pragma unroll
    for (int i = 0; i < 4; ++i)
#pragma unroll
        for (int j = 0; j < 4; ++j) {
            int col = n0 + wn * 64 + j * 16 + lr;
            float bb = bo[col];
#pragma unroll
            for (int q = 0; q < 4; ++q) {
                int row = m0 + wm * 64 + i * 16 + lg * 4 + q;
                out[(size_t)row * D_MODEL + col] = acc[i][j][q] + bb;
            }
        }
}

// ---------------- fused causal attention: two-pass, per-tile NT stores, high occupancy ----------------
// grid (128 chunks of 16 q-rows, B*H); 4 waves/block; each wave owns tiles st%4==w.
// Pass 1: QK^T -> row sums l (fixed max 16). Pass 2 per tile: QK^T recompute,
// p = exp(S-16)*invl (normalized NOW), bf16 mini-tile (16x64, per-wave LDS),
// PV MFMA (all 4 d-quarters; cross-wave reduce at end), then 4 NT store instrs
// (4 rows x 256B) INSIDE the tile loop -> stores issue continuously for the
// whole kernel instead of a terminal phase-C burst (R11's 42% duty cycle).
// Small LDS (~26KB vs 66KB) doubles blocks/CU.
__global__ __launch_bounds__(256) void k_attn(const unsigned short* __restrict__ Qb,
                                              const unsigned short* __restrict__ Kb,
                                              const unsigned short* __restrict__ Vt,
                                              float* __restrict__ Wout,
                                              unsigned short* __restrict__ Ctx) {
    __shared__ unsigned short ptile[4][16 * 72];  // 9.2 KB: per-wave normalized bf16 P tile
    __shared__ float l4[4][16];
    __shared__ float linv[16];
    __shared__ float redbuf[4][16][64];           // 16 KB: cross-wave PV reduce
    int tid = threadIdx.x, w = tid >> 6, lane = tid & 63, lr = lane & 15, lg = lane >> 4;
    int bh = blockIdx.y, b = bh >> 4, h = bh & 15;
    int chunk = 127 - blockIdx.x;                 // LPT: heavy chunks first
    int t0 = chunk * 16;
    int ntiles = (chunk >> 2) + 1;
    int q_row = t0 + lr;

    const unsigned short* Qh = Qb + (size_t)bh * T_SEQ * DKH;
    const unsigned short* Kh = Kb + (size_t)bh * T_SEQ * DKH;
    const unsigned short* Vh = Vt + (size_t)bh * DKH * T_SEQ;
    float* Whead = Wout + (size_t)bh * T_SEQ * T_SEQ;

    bf16x8 qf[2];
#pragma unroll
    for (int kk = 0; kk < 2; ++kk)
        qf[kk] = *reinterpret_cast<const bf16x8*>(Qh + (size_t)q_row * DKH + kk * 32 + lg * 8);

    // ---- pass 1: row sums l (QK^T, fixed max 16) ----
    float lacc = 0.f;
    for (int st = w; st < ntiles; st += 4) {
        int s0 = st * 64;
        bool diag = (st == ntiles - 1);
#pragma unroll
        for (int cf = 0; cf < 4; ++cf) {
            f32x4 a = (f32x4){0.f, 0.f, 0.f, 0.f};
#pragma unroll
            for (int kk = 0; kk < 2; ++kk) {
                bf16x8 kf = *reinterpret_cast<const bf16x8*>(
                    Kh + (size_t)(s0 + cf * 16 + lr) * DKH + kk * 32 + lg * 8);
                a = __builtin_amdgcn_mfma_f32_16x16x32_bf16(kf, qf[kk], a, 0, 0, 0);
            }
#pragma unroll
            for (int r = 0; r < 4; ++r) {
                int s = s0 + cf * 16 + lg * 4 + r;
                lacc += (diag && s > q_row) ? 0.f : __expf(a[r] - 16.f);
            }
        }
    }
    lacc += __shfl_xor(lacc, 16);
    lacc += __shfl_xor(lacc, 32);
    l4[w][lr] = lacc;
    __syncthreads();
    if (tid < 16) linv[tid] = 1.0f / (l4[0][tid] + l4[1][tid] + l4[2][tid] + l4[3][tid]);
    __syncthreads();
    float invq = linv[lr];

    // ---- pass 2: per tile {QK^T, normalize, PV, NT-store} ----
    f32x4 of[4];
#pragma unroll
    for (int df = 0; df < 4; ++df) of[df] = (f32x4){0.f, 0.f, 0.f, 0.f};

    for (int st = w; st < ntiles; st += 4) {
        int s0 = st * 64;
        bool diag = (st == ntiles - 1);
#pragma unroll
        for (int cf = 0; cf < 4; ++cf) {
            f32x4 a = (f32x4){0.f, 0.f, 0.f, 0.f};
#pragma unroll
            for (int kk = 0; kk < 2; ++kk) {
                bf16x8 kf = *reinterpret_cast<const bf16x8*>(
                    Kh + (size_t)(s0 + cf * 16 + lr) * DKH + kk * 32 + lg * 8);
                a = __builtin_amdgcn_mfma_f32_16x16x32_bf16(kf, qf[kk], a, 0, 0, 0);
            }
            u16x4 pb;
#pragma unroll
            for (int r = 0; r < 4; ++r) {
                int s = s0 + cf * 16 + lg * 4 + r;
                float p = (diag && s > q_row) ? 0.f : __expf(a[r] - 16.f) * invq;
                pb[r] = f2bf(p);
            }
            *reinterpret_cast<u16x4*>(&ptile[w][lr * 72 + cf * 16 + lg * 4]) = pb;
        }
        asm volatile("s_waitcnt lgkmcnt(0)" ::: "memory");
        __builtin_amdgcn_sched_barrier(0);

        // PV: all 4 d-quarters for this tile
        bf16x8 pa[2];
#pragma unroll
        for (int ks = 0; ks < 2; ++ks)
            pa[ks] = *reinterpret_cast<const bf16x8*>(&ptile[w][lr * 72 + ks * 32 + lg * 8]);
#pragma unroll
        for (int df = 0; df < 4; ++df) {
#pragma unroll
            for (int ks = 0; ks < 2; ++ks) {
                bf16x8 vf = *reinterpret_cast<const bf16x8*>(
                    Vh + (size_t)(df * 16 + lr) * T_SEQ + s0 + ks * 32 + lg * 8);
                of[df] = __builtin_amdgcn_mfma_f32_16x16x32_bf16(vf, pa[ks], of[df], 0, 0, 0);
            }
        }

        // NT weight stores for this tile: 4 instrs, 4 rows x 256B each
#pragma unroll
        for (int rb = 0; rb < 4; ++rb) {
            int rl = rb * 4 + (lane >> 4);
            int cl = (lane & 15) * 4;
            u16x4 pb = *reinterpret_cast<const u16x4*>(&ptile[w][rl * 72 + cl]);
            f32x4 v;
#pragma unroll
            for (int r = 0; r < 4; ++r)
                v[r] = __builtin_bit_cast(float, (unsigned)pb[r] << 16);
            __builtin_nontemporal_store(v,
                reinterpret_cast<f32x4*>(Whead + (size_t)(t0 + rl) * T_SEQ + s0 + cl));
        }
    }

    // ---- zero tail tiles (interleaved by wave) ----
    {
        f32x4 z4 = (f32x4){0.f, 0.f, 0.f, 0.f};
        int rl0 = lane >> 4, cl = (lane & 15) * 4;
        for (int st = ntiles; st < 32; ++st) {
            if ((st & 3) != w) continue;
            int s0 = st * 64;
#pragma unroll
            for (int rb = 0; rb < 4; ++rb)
                __builtin_nontemporal_store(z4,
                    reinterpret_cast<f32x4*>(Whead + (size_t)(t0 + rb * 4 + rl0) * T_SEQ + s0 + cl));
        }
    }

    // ---- cross-wave PV reduce + Ctx write ----
#pragma unroll
    for (int df = 0; df < 4; ++df)
#pragma unroll
        for (int r = 0; r < 4; ++r)
            redbuf[w][lr][df * 16 + lg * 4 + r] = of[df][r];
    __syncthreads();
    {
        u16x4 c4;
#pragma unroll
        for (int r = 0; r < 4; ++r) {
            int d = w * 16 + lg * 4 + r;
            c4[r] = f2bf(redbuf[0][lr][d] + redbuf[1][lr][d] + redbuf[2][lr][d] + redbuf[3][lr][d]);
        }
        *reinterpret_cast<u16x4*>(
            &Ctx[((size_t)b * T_SEQ + q_row) * D_MODEL + h * DKH + w * 16 + lg * 4]) = c4;
    }
}

extern "C" void kernel_launch(void* const* d_in, const int* in_sizes, int n_in,
                              void* d_out, int out_size, void* d_ws, size_t ws_size,
                              hipStream_t stream) {
    const float* x  = (const float*)d_in[0];
    const float* Wq = (const float*)d_in[1];
    const float* bq = (const float*)d_in[2];
    const float* Wk = (const float*)d_in[3];
    const float* bk = (const float*)d_in[4];
    const float* Wv = (const float*)d_in[5];
    const float* bv = (const float*)d_in[6];
    const float* Wo = (const float*)d_in[7];
    const float* bo = (const float*)d_in[8];
    float* out = (float*)d_out;

    char* ws = (char*)d_ws;
    unsigned short* Xb  = (unsigned short*)(ws);                 // 8 MB
    unsigned short* Wb  = (unsigned short*)(ws + 8388608);       // 8 MB (Wq,Wk,Wv,Wo)
    unsigned short* Qb  = (unsigned short*)(ws + 16777216);      // 8 MB
    unsigned short* Kb  = (unsigned short*)(ws + 25165824);      // 8 MB
    unsigned short* Vt  = (unsigned short*)(ws + 33554432);      // 8 MB
    unsigned short* Ctx = (unsigned short*)(ws + 41943040);      // 8 MB

    // fp32 -> bf16
    k_cvt<<<4096, 256, 0, stream>>>(x, Xb, OUT0_SZ / 4);
    k_cvt_w<<<dim3(1024, 4), 256, 0, stream>>>(Wq, Wk, Wv, Wo, Wb);

    // QKV projection: grid (M/128, N/128, 3)
    k_gemm_qkv<<<dim3(32, 8, 3), 256, 0, stream>>>(Xb, Wb, bq, bk, bv, Qb, Kb, Vt);

    // fused causal attention + weights materialization (per-tile NT streaming)
    k_attn<<<dim3(128, 32), 256, 0, stream>>>(Qb, Kb, Vt, out + OUT0_SZ, Ctx);

    // output projection
    k_gemm_o<<<dim3(32, 8), 256, 0, stream>>>(Ctx, Wb + 3145728, bo, out);
}

// Round 13
// 262.047 us; speedup vs baseline: 1.3013x; 1.3013x over previous
//
#include <hip/hip_runtime.h>

#define D_MODEL 1024
#define T_SEQ   2048
#define BATCH   2
#define HEADS   16
#define DKH     64
#define M_ROWS  (BATCH*T_SEQ)   // 4096
#define OUT0_SZ (M_ROWS*D_MODEL)  // 4194304
#define PSTR    2060              // P-buffer row stride in bf16 (4120B: bank-spread, 8B-aligned)

typedef short bf16x8 __attribute__((ext_vector_type(8)));
typedef float f32x4  __attribute__((ext_vector_type(4)));
typedef unsigned short u16x4 __attribute__((ext_vector_type(4)));

__device__ __forceinline__ unsigned short f2bf(float f) {
    unsigned u = __builtin_bit_cast(unsigned, f);
    u = (u + 0x7fffu + ((u >> 16) & 1u)) >> 16;
    return (unsigned short)u;
}

__device__ __forceinline__ void gload_lds16(const void* g, void* l) {
    __builtin_amdgcn_global_load_lds(
        (const __attribute__((address_space(1))) void*)g,
        (__attribute__((address_space(3))) void*)l, 16, 0, 0);
}

// ---------------- fp32 -> bf16 convert ----------------
__global__ __launch_bounds__(256) void k_cvt(const float* __restrict__ in,
                                             unsigned short* __restrict__ out, int n4) {
    int i = blockIdx.x * 256 + threadIdx.x;
    if (i >= n4) return;
    float4 v = reinterpret_cast<const float4*>(in)[i];
    ushort4 o;
    o.x = f2bf(v.x); o.y = f2bf(v.y); o.z = f2bf(v.z); o.w = f2bf(v.w);
    reinterpret_cast<ushort4*>(out)[i] = o;
}

// all four weight matrices in one launch (grid.y selects)
__global__ __launch_bounds__(256) void k_cvt_w(const float* __restrict__ w0,
                                               const float* __restrict__ w1,
                                               const float* __restrict__ w2,
                                               const float* __restrict__ w3,
                                               unsigned short* __restrict__ out) {
    const float* src = (blockIdx.y == 0) ? w0 : (blockIdx.y == 1) ? w1 : (blockIdx.y == 2) ? w2 : w3;
    int i = blockIdx.x * 256 + threadIdx.x;          // 262144 float4s per matrix
    float4 v = reinterpret_cast<const float4*>(src)[i];
    ushort4 o;
    o.x = f2bf(v.x); o.y = f2bf(v.y); o.z = f2bf(v.z); o.w = f2bf(v.w);
    reinterpret_cast<ushort4*>(out + (size_t)blockIdx.y * 1048576)[i] = o;
}

// ---------------- shared 128x128 GEMM core (C = A * W^T), K = 1024 ----------------
__device__ __forceinline__ void stage_tile(const unsigned short* __restrict__ g,
                                           int r0, int k0, unsigned short* s, int tid) {
#pragma unroll
    for (int it = 0; it < 4; ++it) {
        int row   = (tid >> 3) + it * 32;
        int kb_sw = (tid & 7) << 4;
        int kb    = kb_sw ^ ((row & 7) << 4);
        const unsigned short* gp = g + (size_t)(r0 + row) * D_MODEL + k0 + (kb >> 1);
        gload_lds16(gp, s + (tid >> 6) * 512 + it * 2048);
    }
}

__device__ __forceinline__ bf16x8 ld_frag(const unsigned short* s, int row, int kbyte) {
    int off = (row << 7) + (kbyte ^ ((row & 7) << 4));
    return *reinterpret_cast<const bf16x8*>(reinterpret_cast<const char*>(s) + off);
}

__device__ __forceinline__ void gemm_core(const unsigned short* __restrict__ A,
                                          const unsigned short* __restrict__ W,
                                          unsigned short* sA, unsigned short* sB,
                                          int m0, int n0, f32x4 (&acc)[4][4], int tid) {
    int lane = tid & 63, lr = lane & 15, lg = lane >> 4;
    int wm = tid >> 7, wn = (tid >> 6) & 1;
#pragma unroll 1
    for (int k0 = 0; k0 < D_MODEL; k0 += 64) {
        stage_tile(A, m0, k0, sA, tid);
        stage_tile(W, n0, k0, sB, tid);
        __syncthreads();
#pragma unroll
        for (int kk = 0; kk < 2; ++kk) {
            bf16x8 a[4], b[4];
#pragma unroll
            for (int f = 0; f < 4; ++f) {
                a[f] = ld_frag(sA, wm * 64 + f * 16 + lr, kk * 64 + lg * 16);
                b[f] = ld_frag(sB, wn * 64 + f * 16 + lr, kk * 64 + lg * 16);
            }
#pragma unroll
            for (int i = 0; i < 4; ++i)
#pragma unroll
                for (int j = 0; j < 4; ++j)
                    acc[i][j] = __builtin_amdgcn_mfma_f32_16x16x32_bf16(a[i], b[j], acc[i][j], 0, 0, 0);
        }
        __syncthreads();
    }
}

// ---------------- QKV projection ----------------
__global__ __launch_bounds__(256) void k_gemm_qkv(const unsigned short* __restrict__ Xb,
                                                  const unsigned short* __restrict__ Wb,
                                                  const float* __restrict__ bq,
                                                  const float* __restrict__ bk,
                                                  const float* __restrict__ bv,
                                                  unsigned short* __restrict__ Qb,
                                                  unsigned short* __restrict__ Kb,
                                                  unsigned short* __restrict__ Vt) {
    __shared__ unsigned short sA[128 * 64];
    __shared__ unsigned short sB[128 * 64];
    int tid = threadIdx.x;
    int m0 = blockIdx.x * 128, n0 = blockIdx.y * 128, z = blockIdx.z;
    const unsigned short* W = Wb + (size_t)z * (D_MODEL * D_MODEL);
    const float* bias = (z == 0) ? bq : (z == 1) ? bk : bv;
    f32x4 acc[4][4];
#pragma unroll
    for (int i = 0; i < 4; ++i)
#pragma unroll
        for (int j = 0; j < 4; ++j) acc[i][j] = (f32x4){0.f, 0.f, 0.f, 0.f};

    gemm_core(Xb, W, sA, sB, m0, n0, acc, tid);

    int lane = tid & 63, lr = lane & 15, lg = lane >> 4;
    int wm = tid >> 7, wn = (tid >> 6) & 1;
    float scl = (z == 0) ? 0.125f : 1.0f;   // fold 1/sqrt(64) into Q
#pragma unroll
    for (int i = 0; i < 4; ++i) {
#pragma unroll
        for (int j = 0; j < 4; ++j) {
            int col = n0 + wn * 64 + j * 16 + lr;       // n = h*64 + d
            float bb = bias[col];
            int h = col >> 6, d = col & 63;
#pragma unroll
            for (int q = 0; q < 4; ++q) {
                int row = m0 + wm * 64 + i * 16 + lg * 4 + q;  // b*T + t
                int b = row >> 11, tt = row & 2047;
                float v = (acc[i][j][q] + bb) * scl;
                unsigned short h16 = f2bf(v);
                size_t bh = (size_t)b * HEADS + h;
                if (z == 2)      Vt[(bh * DKH + d) * T_SEQ + tt] = h16;          // V transposed [bh][d][t]
                else if (z == 0) Qb[(bh * T_SEQ + tt) * DKH + d] = h16;
                else             Kb[(bh * T_SEQ + tt) * DKH + d] = h16;
            }
        }
    }
}

// ---------------- output projection ----------------
__global__ __launch_bounds__(256) void k_gemm_o(const unsigned short* __restrict__ Ctx,
                                                const unsigned short* __restrict__ Wo,
                                                const float* __restrict__ bo,
                                                float* __restrict__ out) {
    __shared__ unsigned short sA[128 * 64];
    __shared__ unsigned short sB[128 * 64];
    int tid = threadIdx.x;
    int m0 = blockIdx.x * 128, n0 = blockIdx.y * 128;
    f32x4 acc[4][4];
#pragma unroll
    for (int i = 0; i < 4; ++i)
#pragma unroll
        for (int j = 0; j < 4; ++j) acc[i][j] = (f32x4){0.f, 0.f, 0.f, 0.f};

    gemm_core(Ctx, Wo, sA, sB, m0, n0, acc, tid);

    int lane = tid & 63, lr = lane & 15, lg = lane >> 4;
    int wm = tid >> 7, wn = (tid >> 6) & 1;
#pragma unroll
    for (int i = 0; i < 4; ++i)
#pragma unroll
        for (int j = 0; j < 4; ++j) {
            int col = n0 + wn * 64 + j * 16 + lr;
            float bb = bo[col];
#pragma unroll
            for (int q = 0; q < 4; ++q) {
                int row = m0 + wm * 64 + i * 16 + lg * 4 + q;
                out[(size_t)row * D_MODEL + col] = acc[i][j][q] + bb;
            }
        }
}

// ---------------- fused causal attention: 8 waves, role-split B/C overlap ----------------
// grid (128 chunks of 16 q-rows, B*H); 512 threads. Same 66KB P-buffer as R11 ->
// 2 blocks/CU but 16 waves/CU (2x TLP vs R11).
// Phase A (all 8 waves): QK^T once (fixed max 16), tiles st%8==w, p' bf16 -> P,
//   partial l. One __syncthreads.
// Then CONCURRENTLY: waves 0-3 = PV (d-quarter w, all tiles) + Ctx write;
//   waves 4-7 = NT weight stores (4 rows x 8KB each, 1KB/instr, zero tail folded).
// Store waves' vmcnt holds only stores (never waited) -> stores issue during
// PV compute instead of as a terminal burst (R11's 42% store duty cycle).
__global__ __launch_bounds__(512) void k_attn(const unsigned short* __restrict__ Qb,
                                              const unsigned short* __restrict__ Kb,
                                              const unsigned short* __restrict__ Vt,
                                              float* __restrict__ Wout,
                                              unsigned short* __restrict__ Ctx) {
    __shared__ unsigned short P[16 * PSTR];   // 65,920 B
    __shared__ float l8[8][16];
    __shared__ float linv[16];
    int tid = threadIdx.x, w = tid >> 6, lane = tid & 63, lr = lane & 15, lg = lane >> 4;
    int bh = blockIdx.y, b = bh >> 4, h = bh & 15;
    int chunk = 127 - blockIdx.x;             // LPT: heavy chunks first
    int t0 = chunk * 16;
    int ntiles = (chunk >> 2) + 1;
    int q_row = t0 + lr;

    const unsigned short* Qh = Qb + (size_t)bh * T_SEQ * DKH;
    const unsigned short* Kh = Kb + (size_t)bh * T_SEQ * DKH;
    const unsigned short* Vh = Vt + (size_t)bh * DKH * T_SEQ;
    float* Whead = Wout + (size_t)bh * T_SEQ * T_SEQ;

    bf16x8 qf[2];
#pragma unroll
    for (int kk = 0; kk < 2; ++kk)
        qf[kk] = *reinterpret_cast<const bf16x8*>(Qh + (size_t)q_row * DKH + kk * 32 + lg * 8);

    // ---- phase A: QK^T once (tiles st%8==w), p' = exp(S-16) -> P, partial l ----
    float lacc = 0.f;
    for (int st = w; st < ntiles; st += 8) {
        int s0 = st * 64;
        bool diag = (st == ntiles - 1);
#pragma unroll
        for (int cf = 0; cf < 4; ++cf) {
            f32x4 a = (f32x4){0.f, 0.f, 0.f, 0.f};
#pragma unroll
            for (int kk = 0; kk < 2; ++kk) {
                bf16x8 kf = *reinterpret_cast<const bf16x8*>(
                    Kh + (size_t)(s0 + cf * 16 + lr) * DKH + kk * 32 + lg * 8);
                a = __builtin_amdgcn_mfma_f32_16x16x32_bf16(kf, qf[kk], a, 0, 0, 0);
            }
            u16x4 pb;
#pragma unroll
            for (int r = 0; r < 4; ++r) {
                int s = s0 + cf * 16 + lg * 4 + r;
                float p = (diag && s > q_row) ? 0.f : __expf(a[r] - 16.f);
                lacc += p;
                pb[r] = f2bf(p);
            }
            *reinterpret_cast<u16x4*>(&P[lr * PSTR + s0 + cf * 16 + lg * 4]) = pb;
        }
    }
    lacc += __shfl_xor(lacc, 16);
    lacc += __shfl_xor(lacc, 32);
    l8[w][lr] = lacc;
    __syncthreads();
    if (tid < 16) {
        float s = 0.f;
#pragma unroll
        for (int i = 0; i < 8; ++i) s += l8[i][tid];
        linv[tid] = 1.0f / s;
    }
    __syncthreads();                           // P + linv visible block-wide

    if (w < 4) {
        // ===== waves 0-3: PV for d-quarter w over ALL tiles + Ctx =====
        float invq = linv[lr];
        f32x4 of = (f32x4){0.f, 0.f, 0.f, 0.f};
        for (int st = 0; st < ntiles; ++st) {
            int s0 = st * 64;
#pragma unroll
            for (int ks = 0; ks < 2; ++ks) {
                bf16x8 pa = *reinterpret_cast<const bf16x8*>(&P[lr * PSTR + s0 + ks * 32 + lg * 8]);
                bf16x8 vf = *reinterpret_cast<const bf16x8*>(
                    Vh + (size_t)(w * 16 + lr) * T_SEQ + s0 + ks * 32 + lg * 8);
                of = __builtin_amdgcn_mfma_f32_16x16x32_bf16(vf, pa, of, 0, 0, 0);
            }
        }
        u16x4 c4;
#pragma unroll
        for (int r = 0; r < 4; ++r) c4[r] = f2bf(of[r] * invq);
        *reinterpret_cast<u16x4*>(
            &Ctx[((size_t)b * T_SEQ + q_row) * D_MODEL + h * DKH + w * 16 + lg * 4]) = c4;
    } else {
        // ===== waves 4-7: NT weight stores, rows (w-4)*4 .. +3, 8KB/row =====
        int vcols = ntiles * 64;
        int wq = w - 4;
#pragma unroll
        for (int rr = 0; rr < 4; ++rr) {
            int row = wq * 4 + rr;
            float invlr = linv[row];
            float* dst = Whead + (size_t)(t0 + row) * T_SEQ;
            const unsigned short* prow = &P[row * PSTR];
#pragma unroll 2
            for (int j = 0; j < 8; ++j) {
                int col = j * 256 + lane * 4;
                f32x4 v = (f32x4){0.f, 0.f, 0.f, 0.f};
                if (col < vcols) {
                    u16x4 pb = *reinterpret_cast<const u16x4*>(&prow[col]);
#pragma unroll
                    for (int r = 0; r < 4; ++r)
                        v[r] = __builtin_bit_cast(float, (unsigned)pb[r] << 16) * invlr;
                }
                __builtin_nontemporal_store(v, reinterpret_cast<f32x4*>(dst + col));
            }
        }
    }
}

extern "C" void kernel_launch(void* const* d_in, const int* in_sizes, int n_in,
                              void* d_out, int out_size, void* d_ws, size_t ws_size,
                              hipStream_t stream) {
    const float* x  = (const float*)d_in[0];
    const float* Wq = (const float*)d_in[1];
    const float* bq = (const float*)d_in[2];
    const float* Wk = (const float*)d_in[3];
    const float* bk = (const float*)d_in[4];
    const float* Wv = (const float*)d_in[5];
    const float* bv = (const float*)d_in[6];
    const float* Wo = (const float*)d_in[7];
    const float* bo = (const float*)d_in[8];
    float* out = (float*)d_out;

    char* ws = (char*)d_ws;
    unsigned short* Xb  = (unsigned short*)(ws);                 // 8 MB
    unsigned short* Wb  = (unsigned short*)(ws + 8388608);       // 8 MB (Wq,Wk,Wv,Wo)
    unsigned short* Qb  = (unsigned short*)(ws + 16777216);      // 8 MB
    unsigned short* Kb  = (unsigned short*)(ws + 25165824);      // 8 MB
    unsigned short* Vt  = (unsigned short*)(ws + 33554432);      // 8 MB
    unsigned short* Ctx = (unsigned short*)(ws + 41943040);      // 8 MB

    // fp32 -> bf16
    k_cvt<<<4096, 256, 0, stream>>>(x, Xb, OUT0_SZ / 4);
    k_cvt_w<<<dim3(1024, 4), 256, 0, stream>>>(Wq, Wk, Wv, Wo, Wb);

    // QKV projection: grid (M/128, N/128, 3)
    k_gemm_qkv<<<dim3(32, 8, 3), 256, 0, stream>>>(Xb, Wb, bq, bk, bv, Qb, Kb, Vt);

    // fused causal attention + weights materialization (role-split store overlap)
    k_attn<<<dim3(128, 32), 512, 0, stream>>>(Qb, Kb, Vt, out + OUT0_SZ, Ctx);

    // output projection
    k_gemm_o<<<dim3(32, 8), 256, 0, stream>>>(Ctx, Wb + 3145728, bo, out);
}